// Round 20
// baseline (110.885 us; speedup 1.0000x reference)
//
#include <hip/hip_runtime.h>
#include <math.h>

typedef __attribute__((ext_vector_type(8))) short bf16x8;
typedef __attribute__((ext_vector_type(4))) float f32x4;
typedef unsigned short ushort_t;

// ---------------- fixed workspace prefix (floats) ----------------
#define WS_B12   0                         // 32
#define WS_B34   32                        // 64
#define WS_WMF12 96                        // 2560 fl (5120 ushort)
#define WS_WMF   2656                      // 82944 fl (165888 ushort)
#define WS_FIX   85600                     // start of variable region

// Disjoint layout (needs ws_size >= 9.75 MB): NO overlays, safe for merged k_mid
#define D_WPART  WS_FIX                    // 1327104 fl
#define D_BPART  (WS_FIX + 1327104)        // 512
#define D_P1     (WS_FIX + 1327616)        // 921600 fl (bf16 x 1843200)
#define D_EMB    (D_P1 + 921600)           // 102400
#define D_TOTAL  (D_EMB + 102400)

// Overlay layout (fallback): Wpart overlays P1 region (serial ordering)
#define O_P1     WS_FIX
#define O_WPART  WS_FIX
#define O_BPART  (WS_FIX + 8*165888)
#define O_EMB    (WS_FIX + 1843200)

__device__ __forceinline__ unsigned short f2bf(float f) {
    unsigned u = __float_as_uint(f);
    u += 0x7FFF + ((u >> 16) & 1);         // RNE
    return (unsigned short)(u >> 16);
}

// ---------------- kernel A: prep12 (+Wmf12 pack)  ||  prep34 partials -----
__global__ __launch_bounds__(256) void k_prepA(
    const float* __restrict__ w1, const float* __restrict__ b1,
    const float* __restrict__ w2, const float* __restrict__ b2,
    const float* __restrict__ w3, const float* __restrict__ b3,
    const float* __restrict__ w4,
    float* __restrict__ B12, ushort_t* __restrict__ Wmf12,
    float* __restrict__ Wpart, float* __restrict__ Bpart)
{
    __shared__ float smem[13664];          // 54.7 KB
    int t = threadIdx.x;

    if (blockIdx.x < 32) {
        float* sW2  = smem;            // [mc*25+e]
        float* sW1  = smem + 800;
        float* sW12 = smem + 1600;     // [uv 81]
        int oc = blockIdx.x;
        for (int i = t; i < 800; i += 256) {
            sW2[i] = w2[oc * 800 + i];
            sW1[i] = w1[i];
        }
        __syncthreads();
        if (t < 81) {
            int u = t / 9, v = t % 9;
            float acc[4] = {0.f, 0.f, 0.f, 0.f};
            #pragma unroll
            for (int e = 0; e < 25; ++e) {
                int ey = e / 5, ex = e % 5;
                int du = u - ey, dv = v - ex;
                if ((unsigned)du <= 4u && (unsigned)dv <= 4u) {
                    int ep = du * 5 + dv;
                    for (int mc = 0; mc < 32; ++mc)
                        acc[e & 3] = fmaf(sW2[mc * 25 + e], sW1[mc * 25 + ep],
                                          acc[e & 3]);
                }
            }
            sW12[t] = (acc[0] + acc[1]) + (acc[2] + acc[3]);
        }
        if (t < 32) {
            float ws = 0.f;
            #pragma unroll
            for (int e = 0; e < 25; ++e) ws += sW2[t * 25 + e];
            float p = b1[t] * ws;
            #pragma unroll
            for (int off = 16; off; off >>= 1) p += __shfl_down(p, off, 64);
            if (t == 0) B12[oc] = p + b2[oc];
        }
        __syncthreads();
        if (t < 160) {                 // pack bf16 K-tap layout (pads = 0)
            int s  = t >> 5;
            int kc = (t >> 3) & 3;
            int e  = t & 7;
            int ky = 2 * s + (kc >> 1);
            int kx = 8 * (kc & 1) + e;
            float v = (ky <= 8 && kx <= 8) ? sW12[ky * 9 + kx] : 0.f;
            int so = s * 2 + (oc >> 4);
            int i2 = (so << 9) | (kc << 7) | ((oc & 15) << 3) | e;
            Wmf12[i2] = f2bf(v);
        }
    } else {
        float* sW4  = smem;            // [oc 64][201]
        float* sW3c = smem + 64 * 201; // [mcl 8][icl 4][e 25]
        int bid = blockIdx.x - 32;
        int icg = bid >> 3;
        int mcc = bid & 7;
        int oc  = t & 63;
        int icl = t >> 6;              // wave-uniform

        for (int i = t; i < 12800; i += 256) {
            int o = i / 200, r = i % 200;
            sW4[o * 201 + r] = w4[o * 1600 + mcc * 200 + r];
        }
        for (int i = t; i < 800; i += 256) {
            int mcl = i / 100, r = i % 100;
            sW3c[i] = w3[(mcc * 8 + mcl) * 800 + icg * 100 + r];
        }
        __syncthreads();

        float acc[81];
        #pragma unroll
        for (int u = 0; u < 81; ++u) acc[u] = 0.f;
        float bacc = 0.f;

        for (int mcl = 0; mcl < 8; ++mcl) {
            float w4r[25];
            #pragma unroll
            for (int e = 0; e < 25; ++e)
                w4r[e] = sW4[oc * 201 + mcl * 25 + e];
            const float* w3r = &sW3c[(mcl * 4 + icl) * 25];
            #pragma unroll
            for (int e2 = 0; e2 < 25; ++e2) {
                int ey = e2 / 5, ex = e2 % 5;
                #pragma unroll
                for (int e1 = 0; e1 < 25; ++e1) {
                    int u = (ey + e1 / 5) * 9 + (ex + e1 % 5); // compile-time
                    acc[u] = fmaf(w4r[e2], w3r[e1], acc[u]);
                }
            }
            if (icl == 0) {
                float ws = 0.f;
                #pragma unroll
                for (int e = 0; e < 25; ++e) ws += w4r[e];
                bacc = fmaf(b3[mcc * 8 + mcl], ws, bacc);
            }
        }

        int ic = icg * 4 + icl;
        for (int uv = 0; uv < 81; ++uv)
            Wpart[((mcc * 32 + ic) * 81 + uv) * 64 + oc] = acc[uv];
        if (icl == 0) Bpart[mcc * 64 + oc] = bacc;
    }
}

// ---------------- standalone prep34s (fallback path) ----------------------
__global__ __launch_bounds__(256) void k_prep34s(
    const float* __restrict__ Wpart, const float* __restrict__ Bpart,
    const float* __restrict__ b4,
    ushort_t* __restrict__ Wmf, float* __restrict__ B34)
{
    int i = blockIdx.x * 256 + threadIdx.x;
    if (i < 165888) {
        float s = 0.f;
        #pragma unroll
        for (int c = 0; c < 8; ++c) s += Wpart[c * 165888 + i];
        int oc = i & 63, r = i >> 6;
        int ic = r / 81, uv = r % 81;
        int idx = (uv * 16 + (oc >> 4) * 4 + (ic >> 3)) * 128
                + (oc & 15) * 8 + (ic & 7);
        Wmf[idx] = f2bf(s);
    }
    if (blockIdx.x == 648 && threadIdx.x < 64) {
        int oc = threadIdx.x;
        float s = b4[oc];
        #pragma unroll
        for (int c = 0; c < 8; ++c) s += Bpart[c * 64 + oc];
        B34[oc] = s;
    }
}

// ---------------- conv12m body (shared by k_conv12m and k_mid) ------------
__device__ __forceinline__ void conv12m_body(
    int bid, int t,
    const float* __restrict__ x, const ushort_t* __restrict__ Wmf12,
    const float* __restrict__ B12, ushort_t* __restrict__ P1bf,
    ushort_t* sX)
{
    int b  = bid / 30;
    int py = bid % 30;

    if (t < 221) {
        int rowL = t / 17, qg = t % 17;
        int absrow = 4 * py + rowL;
        if (absrow > 127) absrow = 127;
        const float* xr = x + (b * 128 + absrow) * 128;
        int c0 = qg * 8;
        float fs[16];
        #pragma unroll
        for (int q4 = 0; q4 < 4; ++q4) {
            int c = c0 + 4 * q4;
            float4 f;
            if (c <= 124) f = *(const float4*)(xr + c);
            else { f.x = 0.f; f.y = 0.f; f.z = 0.f; f.w = 0.f; }
            fs[4 * q4 + 0] = f.x; fs[4 * q4 + 1] = f.y;
            fs[4 * q4 + 2] = f.z; fs[4 * q4 + 3] = f.w;
        }
        unsigned d[8];
        #pragma unroll
        for (int j = 0; j < 8; ++j)
            d[j] = (unsigned)f2bf(fs[2 * j]) |
                   ((unsigned)f2bf(fs[2 * j + 1]) << 16);
        int eoff = rowL * 144 + c0;
        #pragma unroll
        for (int p = 0; p < 8; ++p) {
            uint4 wv;
            int k = p >> 1;
            if ((p & 1) == 0) {
                wv.x = d[k]; wv.y = d[k + 1]; wv.z = d[k + 2]; wv.w = d[k + 3];
            } else {
                wv.x = (d[k] >> 16)     | (d[k + 1] << 16);
                wv.y = (d[k + 1] >> 16) | (d[k + 2] << 16);
                wv.z = (d[k + 2] >> 16) | (d[k + 3] << 16);
                wv.w = (d[k + 3] >> 16) | (d[k + 4] << 16);
            }
            *(uint4*)(sX + p * 1880 + eoff) = wv;
        }
    }

    int l   = t & 63;
    int wv_ = t >> 6;
    int m16 = l & 15;
    int kc  = l >> 4;

    bf16x8 Bf[5][2];
    {
        const ushort_t* wb = Wmf12 + kc * 128 + m16 * 8;
        #pragma unroll
        for (int s = 0; s < 5; ++s)
            #pragma unroll
            for (int och = 0; och < 2; ++och)
                Bf[s][och] = *(const bf16x8*)(wb + (s * 2 + och) * 512);
    }
    float bias0 = B12[m16];
    float bias1 = B12[16 + m16];
    __syncthreads();

    int baseC = (m16 & 7) * 1880 + (kc >> 1) * 144
              + 8 * (m16 >> 3) + 8 * (kc & 1);

    #pragma unroll
    for (int xi = 0; xi < 2; ++xi) {
        int xt = wv_ * 2 + xi;
        const ushort_t* ap = sX + baseC + xt * 16;
        bf16x8 T[12];
        #pragma unroll
        for (int r = 0; r < 12; ++r)
            T[r] = *(const bf16x8*)(ap + r * 144);

        float pm0 = -INFINITY, pm1 = -INFINITY;
        #pragma unroll
        for (int y = 0; y < 4; ++y) {
            f32x4 a0 = {0.f, 0.f, 0.f, 0.f}, a1 = a0;
            #pragma unroll
            for (int s = 0; s < 5; ++s) {
                a0 = __builtin_amdgcn_mfma_f32_16x16x32_bf16(T[y + 2 * s], Bf[s][0], a0, 0, 0, 0);
                a1 = __builtin_amdgcn_mfma_f32_16x16x32_bf16(T[y + 2 * s], Bf[s][1], a1, 0, 0, 0);
            }
            pm0 = fmaxf(pm0, fmaxf(fmaxf(a0[0], a0[1]), fmaxf(a0[2], a0[3])));
            pm1 = fmaxf(pm1, fmaxf(fmaxf(a1[0], a1[1]), fmaxf(a1[2], a1[3])));
        }
        int px = xt * 4 + (l >> 4);
        if (px < 30) {
            int ob = ((b * 30 + py) * 30 + px) * 32 + m16;
            P1bf[ob]      = f2bf(pm0 + bias0);
            P1bf[ob + 16] = f2bf(pm1 + bias1);
        }
    }
}

// ---------------- kernel B (fallback): conv12m alone ----------------------
__global__ __launch_bounds__(256, 2) void k_conv12m(
    const float* __restrict__ x, const ushort_t* __restrict__ Wmf12,
    const float* __restrict__ B12, ushort_t* __restrict__ P1bf)
{
    __shared__ ushort_t sX[8 * 1880];
    conv12m_body(blockIdx.x, threadIdx.x, x, Wmf12, B12, P1bf, sX);
}

// ---------------- kernel B' (merged): conv12m || prep34s ------------------
// SAFE only with the disjoint layout (Wpart and P1bf non-overlapping).
__global__ __launch_bounds__(256, 2) void k_mid(
    const float* __restrict__ x, const ushort_t* __restrict__ Wmf12,
    const float* __restrict__ B12, ushort_t* __restrict__ P1bf,
    const float* __restrict__ Wpart, const float* __restrict__ Bpart,
    const float* __restrict__ b4,
    ushort_t* __restrict__ Wmf, float* __restrict__ B34)
{
    __shared__ ushort_t sX[8 * 1880];
    int t = threadIdx.x;
    if (blockIdx.x >= 1920) {
        int bid2 = blockIdx.x - 1920;
        int i = bid2 * 256 + t;
        if (i < 165888) {
            float s = 0.f;
            #pragma unroll
            for (int c = 0; c < 8; ++c) s += Wpart[c * 165888 + i];
            int oc = i & 63, r = i >> 6;
            int ic = r / 81, uv = r % 81;
            int idx = (uv * 16 + (oc >> 4) * 4 + (ic >> 3)) * 128
                    + (oc & 15) * 8 + (ic & 7);
            Wmf[idx] = f2bf(s);
        }
        if (bid2 == 648 && t < 64) {
            int oc = t;
            float s = b4[oc];
            #pragma unroll
            for (int c = 0; c < 8; ++c) s += Bpart[c * 64 + oc];
            B34[oc] = s;
        }
        return;
    }
    conv12m_body(blockIdx.x, t, x, Wmf12, B12, P1bf, sX);
}

// ---------------- kernel C: conv34 via MFMA + fused 4x4 pool -> emb -------
__global__ __launch_bounds__(320, 1) void k_conv34m(
    const ushort_t* __restrict__ P1bf, const ushort_t* __restrict__ Wmf,
    const float* __restrict__ B34, float* __restrict__ emb)
{
    __shared__ ushort_t sA[28 * 960];   // 53760 B

    int b  = blockIdx.x >> 2;
    int nt = blockIdx.x & 3;
    int t  = threadIdx.x;

    const uint4* gsrc = (const uint4*)(P1bf + b * 28800);
    for (int i = t; i < 3360; i += 320)
        ((uint4*)sA)[i] = gsrc[i];
    __syncthreads();

    int w  = t >> 6;          // wave = pool row py
    int l  = t & 63;
    int m16 = l & 15;
    int kc  = l >> 4;
    int iy = m16 >> 2, ix = m16 & 3;

    f32x4 acc0 = {0.f,0.f,0.f,0.f}, acc1 = acc0, acc2 = acc0,
          acc3 = acc0, acc4 = acc0;

    const ushort_t* wp = Wmf + (nt * 4 + kc) * 128 + m16 * 8;
    bf16x8 bcur = *(const bf16x8*)wp;
    int tap = 0;

    for (int ky = 0; ky < 9; ++ky) {
        const ushort_t* rp = sA + (w * 4 + iy + ky) * 960 + ix * 32 + kc * 8;
        bf16x8 T[25];
        #pragma unroll
        for (int cx = 0; cx < 25; ++cx)
            T[cx] = *(const bf16x8*)(rp + cx * 32);

        #pragma unroll
        for (int kx = 0; kx < 9; ++kx) {
            bf16x8 bnext = *(const bf16x8*)(wp + (tap + 1) * 2048);
            acc0 = __builtin_amdgcn_mfma_f32_16x16x32_bf16(T[kx],      bcur, acc0, 0, 0, 0);
            acc1 = __builtin_amdgcn_mfma_f32_16x16x32_bf16(T[kx + 4],  bcur, acc1, 0, 0, 0);
            acc2 = __builtin_amdgcn_mfma_f32_16x16x32_bf16(T[kx + 8],  bcur, acc2, 0, 0, 0);
            acc3 = __builtin_amdgcn_mfma_f32_16x16x32_bf16(T[kx + 12], bcur, acc3, 0, 0, 0);
            acc4 = __builtin_amdgcn_mfma_f32_16x16x32_bf16(T[kx + 16], bcur, acc4, 0, 0, 0);
            bcur = bnext;
            ++tap;
        }
    }

    float bias = B34[nt * 16 + m16];
    #pragma unroll
    for (int q = 0; q < 5; ++q) {
        f32x4 a = (q == 0) ? acc0 : (q == 1) ? acc1 : (q == 2) ? acc2
                : (q == 3) ? acc3 : acc4;
        float mv = fmaxf(fmaxf(a[0], a[1]), fmaxf(a[2], a[3]));
        mv = fmaxf(mv, __shfl_xor(mv, 16, 64));
        mv = fmaxf(mv, __shfl_xor(mv, 32, 64));
        if (l < 16) {
            int oc = nt * 16 + l;
            emb[b * 1600 + oc * 25 + w * 5 + q] = mv + bias;
        }
    }
}

// ---------------- kernel D: FULL fc (fc1+relu+fc2 cols+sigmoid product) ---
// grid = 64 (one block per batch); block = 1024 = 4 seg (head x kh) x 256 j.
// Same per-thread work & coalesced W1 pattern as the proven k_fc; the whole
// epilogue (bias, relu, 3 fc2 columns, sigmoids, product) finishes in-block.
__global__ __launch_bounds__(1024) void k_fcf(
    const float* __restrict__ emb,
    const float* __restrict__ w_ed1, const float* __restrict__ b_ed1,
    const float* __restrict__ w_ed2, const float* __restrict__ b_ed2,
    const float* __restrict__ w_ep1, const float* __restrict__ b_ep1,
    const float* __restrict__ w_ep2, const float* __restrict__ b_ep2,
    const int* __restrict__ esrc, const int* __restrict__ edst,
    float* __restrict__ out)
{
    __shared__ float se[1600];
    __shared__ float sh[4][256];       // [head*2+kh][j]
    __shared__ float sp[3];

    int b   = blockIdx.x;
    int t   = threadIdx.x;
    int j   = t & 255;
    int seg = t >> 8;                  // 0..3, wave-uniform
    int head = seg >> 1;
    int kh   = seg & 1;

    {
        const float4* src = (const float4*)(emb + b * 1600);
        for (int i = t; i < 400; i += 1024) ((float4*)se)[i] = src[i];
    }
    __syncthreads();

    const float* W1 = head ? w_ep1 : w_ed1;
    float a0 = 0.f, a1 = 0.f, a2 = 0.f, a3 = 0.f;
    int k0 = kh * 800;
    #pragma unroll 8
    for (int k = k0; k < k0 + 800; k += 4) {
        a0 = fmaf(se[k + 0], W1[(k + 0) * 256 + j], a0);
        a1 = fmaf(se[k + 1], W1[(k + 1) * 256 + j], a1);
        a2 = fmaf(se[k + 2], W1[(k + 2) * 256 + j], a2);
        a3 = fmaf(se[k + 3], W1[(k + 3) * 256 + j], a3);
    }
    sh[seg][j] = (a0 + a1) + (a2 + a3);
    __syncthreads();

    // bias + relu -> se[head*256 + j] (se is dead now)
    if (t < 512) {
        int h2 = t >> 8;
        float bias1 = h2 ? b_ep1[j] : b_ed1[j];
        se[h2 * 256 + j] = fmaxf(bias1 + sh[h2 * 2][j] + sh[h2 * 2 + 1][j],
                                 0.f);
    }
    __syncthreads();

    int c0 = esrc[0], c1 = edst[0];
    if (t < 192) {
        int q    = t >> 6;             // wave-uniform 0..2
        int lane = t & 63;
        int hd   = q > 0;
        float acc = 0.f;
        #pragma unroll
        for (int it = 0; it < 4; ++it) {
            int jj = lane + it * 64;
            float h = se[hd * 256 + jj];
            float w = (q == 0) ? w_ed2[jj * 120]
                    : (q == 1) ? w_ep2[jj * 36 + c0] : w_ep2[jj * 36 + c1];
            acc = fmaf(h, w, acc);
        }
        #pragma unroll
        for (int off = 32; off; off >>= 1) acc += __shfl_down(acc, off, 64);
        if (lane == 0) sp[q] = acc;
    }
    __syncthreads();
    if (t == 0) {
        float l0 = sp[0] + b_ed2[0];
        float l1 = sp[1] + b_ep2[c0];
        float l2 = sp[2] + b_ep2[c1];
        out[b] = (1.f / (1.f + expf(-l0))) *
                 (1.f / (1.f + expf(-l1))) *
                 (1.f / (1.f + expf(-l2)));
    }
}

// ---------------- launch --------------------------------------------------
extern "C" void kernel_launch(void* const* d_in, const int* in_sizes, int n_in,
                              void* d_out, int out_size, void* d_ws, size_t ws_size,
                              hipStream_t stream)
{
    const float* x     = (const float*)d_in[0];
    const float* w1    = (const float*)d_in[1];
    const float* b1    = (const float*)d_in[2];
    const float* w2    = (const float*)d_in[3];
    const float* b2    = (const float*)d_in[4];
    const float* w3    = (const float*)d_in[5];
    const float* b3    = (const float*)d_in[6];
    const float* w4    = (const float*)d_in[7];
    const float* b4    = (const float*)d_in[8];
    const float* w_ed1 = (const float*)d_in[9];
    const float* b_ed1 = (const float*)d_in[10];
    const float* w_ed2 = (const float*)d_in[11];
    const float* b_ed2 = (const float*)d_in[12];
    const float* w_ep1 = (const float*)d_in[13];
    const float* b_ep1 = (const float*)d_in[14];
    const float* w_ep2 = (const float*)d_in[15];
    const float* b_ep2 = (const float*)d_in[16];
    const int*   esrc  = (const int*)d_in[17];
    const int*   edst  = (const int*)d_in[18];

    float* ws  = (float*)d_ws;
    float* out = (float*)d_out;

    ushort_t* Wmf12 = (ushort_t*)(ws + WS_WMF12);
    ushort_t* Wmf   = (ushort_t*)(ws + WS_WMF);

    if (ws_size >= (size_t)D_TOTAL * 4) {
        // ---- disjoint layout, merged middle kernel (4 launches) ----
        ushort_t* P1bf = (ushort_t*)(ws + D_P1);
        k_prepA<<<96, 256, 0, stream>>>(w1, b1, w2, b2, w3, b3, w4,
                                        ws + WS_B12, Wmf12,
                                        ws + D_WPART, ws + D_BPART);
        k_mid<<<1920 + 649, 256, 0, stream>>>(x, Wmf12, ws + WS_B12, P1bf,
                                              ws + D_WPART, ws + D_BPART, b4,
                                              Wmf, ws + WS_B34);
        k_conv34m<<<256, 320, 0, stream>>>(P1bf, Wmf, ws + WS_B34, ws + D_EMB);
        k_fcf<<<64, 1024, 0, stream>>>(ws + D_EMB, w_ed1, b_ed1, w_ed2, b_ed2,
                                       w_ep1, b_ep1, w_ep2, b_ep2, esrc, edst,
                                       out);
    } else {
        // ---- overlay fallback: serial (5 launches) ----
        ushort_t* P1bf = (ushort_t*)(ws + O_P1);
        k_prepA<<<96, 256, 0, stream>>>(w1, b1, w2, b2, w3, b3, w4,
                                        ws + WS_B12, Wmf12,
                                        ws + O_WPART, ws + O_BPART);
        k_prep34s<<<649, 256, 0, stream>>>(ws + O_WPART, ws + O_BPART, b4,
                                           Wmf, ws + WS_B34);
        k_conv12m<<<64 * 30, 256, 0, stream>>>(x, Wmf12, ws + WS_B12, P1bf);
        k_conv34m<<<256, 320, 0, stream>>>(P1bf, Wmf, ws + WS_B34, ws + O_EMB);
        k_fcf<<<64, 1024, 0, stream>>>(ws + O_EMB, w_ed1, b_ed1, w_ed2, b_ed2,
                                       w_ep1, b_ep1, w_ep2, b_ep2, esrc, edst,
                                       out);
    }
}

// Round 21
// 76.522 us; speedup vs baseline: 1.4491x; 1.4491x over previous
//
#include <hip/hip_runtime.h>
#include <math.h>

typedef __attribute__((ext_vector_type(8))) short bf16x8;
typedef __attribute__((ext_vector_type(4))) float f32x4;
typedef unsigned short ushort_t;

// ---------------- fixed workspace prefix (floats) ----------------
#define WS_B12   0                         // 32
#define WS_B34   32                        // 64
#define WS_WMF12 96                        // 2560 fl (5120 ushort)
#define WS_WMF   2656                      // 82944 fl (165888 ushort)
#define WS_FIX   85600                     // start of variable region

// Disjoint layout (needs ws_size >= ~9.8 MB): NO overlays, safe for merged k_mid
#define D_WPART  WS_FIX                    // 1327104 fl
#define D_BPART  (WS_FIX + 1327104)        // 512
#define D_P1     (WS_FIX + 1327616)        // 921600 fl (bf16 x 1843200)
#define D_EMB    (D_P1 + 921600)           // 102400
#define D_LOG    (D_EMB + 102400)          // 192
#define D_CNT    (D_LOG + 192)             // 64 (ints)
#define D_TOTAL  (D_CNT + 64)

// Overlay layout (fallback): Wpart overlays P1 region (serial ordering)
#define O_P1     WS_FIX
#define O_WPART  WS_FIX
#define O_BPART  (WS_FIX + 8*165888)
#define O_EMB    (WS_FIX + 1843200)
#define O_LOG    (O_EMB + 102400)
#define O_CNT    (O_LOG + 192)

__device__ __forceinline__ unsigned short f2bf(float f) {
    unsigned u = __float_as_uint(f);
    u += 0x7FFF + ((u >> 16) & 1);         // RNE
    return (unsigned short)(u >> 16);
}

// ---------------- kernel A: prep12 (+Wmf12 pack)  ||  prep34 partials -----
// Block 0 additionally zeroes the per-batch completion counters.
__global__ __launch_bounds__(256) void k_prepA(
    const float* __restrict__ w1, const float* __restrict__ b1,
    const float* __restrict__ w2, const float* __restrict__ b2,
    const float* __restrict__ w3, const float* __restrict__ b3,
    const float* __restrict__ w4,
    float* __restrict__ B12, ushort_t* __restrict__ Wmf12,
    float* __restrict__ Wpart, float* __restrict__ Bpart,
    int* __restrict__ cnt)
{
    __shared__ float smem[13664];          // 54.7 KB
    int t = threadIdx.x;

    if (blockIdx.x == 0 && t >= 192) {     // zero counters (t 192..255 -> 64)
        cnt[t - 192] = 0;
    }

    if (blockIdx.x < 32) {
        float* sW2  = smem;            // [mc*25+e]
        float* sW1  = smem + 800;
        float* sW12 = smem + 1600;     // [uv 81]
        int oc = blockIdx.x;
        for (int i = t; i < 800; i += 256) {
            sW2[i] = w2[oc * 800 + i];
            sW1[i] = w1[i];
        }
        __syncthreads();
        if (t < 81) {
            int u = t / 9, v = t % 9;
            float acc[4] = {0.f, 0.f, 0.f, 0.f};
            #pragma unroll
            for (int e = 0; e < 25; ++e) {
                int ey = e / 5, ex = e % 5;
                int du = u - ey, dv = v - ex;
                if ((unsigned)du <= 4u && (unsigned)dv <= 4u) {
                    int ep = du * 5 + dv;
                    for (int mc = 0; mc < 32; ++mc)
                        acc[e & 3] = fmaf(sW2[mc * 25 + e], sW1[mc * 25 + ep],
                                          acc[e & 3]);
                }
            }
            sW12[t] = (acc[0] + acc[1]) + (acc[2] + acc[3]);
        }
        if (t < 32) {
            float ws = 0.f;
            #pragma unroll
            for (int e = 0; e < 25; ++e) ws += sW2[t * 25 + e];
            float p = b1[t] * ws;
            #pragma unroll
            for (int off = 16; off; off >>= 1) p += __shfl_down(p, off, 64);
            if (t == 0) B12[oc] = p + b2[oc];
        }
        __syncthreads();
        if (t < 160) {                 // pack bf16 K-tap layout (pads = 0)
            int s  = t >> 5;
            int kc = (t >> 3) & 3;
            int e  = t & 7;
            int ky = 2 * s + (kc >> 1);
            int kx = 8 * (kc & 1) + e;
            float v = (ky <= 8 && kx <= 8) ? sW12[ky * 9 + kx] : 0.f;
            int so = s * 2 + (oc >> 4);
            int i2 = (so << 9) | (kc << 7) | ((oc & 15) << 3) | e;
            Wmf12[i2] = f2bf(v);
        }
    } else {
        float* sW4  = smem;            // [oc 64][201]
        float* sW3c = smem + 64 * 201; // [mcl 8][icl 4][e 25]
        int bid = blockIdx.x - 32;
        int icg = bid >> 3;
        int mcc = bid & 7;
        int oc  = t & 63;
        int icl = t >> 6;              // wave-uniform

        for (int i = t; i < 12800; i += 256) {
            int o = i / 200, r = i % 200;
            sW4[o * 201 + r] = w4[o * 1600 + mcc * 200 + r];
        }
        for (int i = t; i < 800; i += 256) {
            int mcl = i / 100, r = i % 100;
            sW3c[i] = w3[(mcc * 8 + mcl) * 800 + icg * 100 + r];
        }
        __syncthreads();

        float acc[81];
        #pragma unroll
        for (int u = 0; u < 81; ++u) acc[u] = 0.f;
        float bacc = 0.f;

        for (int mcl = 0; mcl < 8; ++mcl) {
            float w4r[25];
            #pragma unroll
            for (int e = 0; e < 25; ++e)
                w4r[e] = sW4[oc * 201 + mcl * 25 + e];
            const float* w3r = &sW3c[(mcl * 4 + icl) * 25];
            #pragma unroll
            for (int e2 = 0; e2 < 25; ++e2) {
                int ey = e2 / 5, ex = e2 % 5;
                #pragma unroll
                for (int e1 = 0; e1 < 25; ++e1) {
                    int u = (ey + e1 / 5) * 9 + (ex + e1 % 5); // compile-time
                    acc[u] = fmaf(w4r[e2], w3r[e1], acc[u]);
                }
            }
            if (icl == 0) {
                float ws = 0.f;
                #pragma unroll
                for (int e = 0; e < 25; ++e) ws += w4r[e];
                bacc = fmaf(b3[mcc * 8 + mcl], ws, bacc);
            }
        }

        int ic = icg * 4 + icl;
        for (int uv = 0; uv < 81; ++uv)
            Wpart[((mcc * 32 + ic) * 81 + uv) * 64 + oc] = acc[uv];
        if (icl == 0) Bpart[mcc * 64 + oc] = bacc;
    }
}

// ---------------- standalone prep34s (fallback path) ----------------------
__global__ __launch_bounds__(256) void k_prep34s(
    const float* __restrict__ Wpart, const float* __restrict__ Bpart,
    const float* __restrict__ b4,
    ushort_t* __restrict__ Wmf, float* __restrict__ B34)
{
    int i = blockIdx.x * 256 + threadIdx.x;
    if (i < 165888) {
        float s = 0.f;
        #pragma unroll
        for (int c = 0; c < 8; ++c) s += Wpart[c * 165888 + i];
        int oc = i & 63, r = i >> 6;
        int ic = r / 81, uv = r % 81;
        int idx = (uv * 16 + (oc >> 4) * 4 + (ic >> 3)) * 128
                + (oc & 15) * 8 + (ic & 7);
        Wmf[idx] = f2bf(s);
    }
    if (blockIdx.x == 648 && threadIdx.x < 64) {
        int oc = threadIdx.x;
        float s = b4[oc];
        #pragma unroll
        for (int c = 0; c < 8; ++c) s += Bpart[c * 64 + oc];
        B34[oc] = s;
    }
}

// ---------------- conv12m body (shared by k_conv12m and k_mid) ------------
__device__ __forceinline__ void conv12m_body(
    int bid, int t,
    const float* __restrict__ x, const ushort_t* __restrict__ Wmf12,
    const float* __restrict__ B12, ushort_t* __restrict__ P1bf,
    ushort_t* sX)
{
    int b  = bid / 30;
    int py = bid % 30;

    if (t < 221) {
        int rowL = t / 17, qg = t % 17;
        int absrow = 4 * py + rowL;
        if (absrow > 127) absrow = 127;
        const float* xr = x + (b * 128 + absrow) * 128;
        int c0 = qg * 8;
        float fs[16];
        #pragma unroll
        for (int q4 = 0; q4 < 4; ++q4) {
            int c = c0 + 4 * q4;
            float4 f;
            if (c <= 124) f = *(const float4*)(xr + c);
            else { f.x = 0.f; f.y = 0.f; f.z = 0.f; f.w = 0.f; }
            fs[4 * q4 + 0] = f.x; fs[4 * q4 + 1] = f.y;
            fs[4 * q4 + 2] = f.z; fs[4 * q4 + 3] = f.w;
        }
        unsigned d[8];
        #pragma unroll
        for (int j = 0; j < 8; ++j)
            d[j] = (unsigned)f2bf(fs[2 * j]) |
                   ((unsigned)f2bf(fs[2 * j + 1]) << 16);
        int eoff = rowL * 144 + c0;
        #pragma unroll
        for (int p = 0; p < 8; ++p) {
            uint4 wv;
            int k = p >> 1;
            if ((p & 1) == 0) {
                wv.x = d[k]; wv.y = d[k + 1]; wv.z = d[k + 2]; wv.w = d[k + 3];
            } else {
                wv.x = (d[k] >> 16)     | (d[k + 1] << 16);
                wv.y = (d[k + 1] >> 16) | (d[k + 2] << 16);
                wv.z = (d[k + 2] >> 16) | (d[k + 3] << 16);
                wv.w = (d[k + 3] >> 16) | (d[k + 4] << 16);
            }
            *(uint4*)(sX + p * 1880 + eoff) = wv;
        }
    }

    int l   = t & 63;
    int wv_ = t >> 6;
    int m16 = l & 15;
    int kc  = l >> 4;

    bf16x8 Bf[5][2];
    {
        const ushort_t* wb = Wmf12 + kc * 128 + m16 * 8;
        #pragma unroll
        for (int s = 0; s < 5; ++s)
            #pragma unroll
            for (int och = 0; och < 2; ++och)
                Bf[s][och] = *(const bf16x8*)(wb + (s * 2 + och) * 512);
    }
    float bias0 = B12[m16];
    float bias1 = B12[16 + m16];
    __syncthreads();

    int baseC = (m16 & 7) * 1880 + (kc >> 1) * 144
              + 8 * (m16 >> 3) + 8 * (kc & 1);

    #pragma unroll
    for (int xi = 0; xi < 2; ++xi) {
        int xt = wv_ * 2 + xi;
        const ushort_t* ap = sX + baseC + xt * 16;
        bf16x8 T[12];
        #pragma unroll
        for (int r = 0; r < 12; ++r)
            T[r] = *(const bf16x8*)(ap + r * 144);

        float pm0 = -INFINITY, pm1 = -INFINITY;
        #pragma unroll
        for (int y = 0; y < 4; ++y) {
            f32x4 a0 = {0.f, 0.f, 0.f, 0.f}, a1 = a0;
            #pragma unroll
            for (int s = 0; s < 5; ++s) {
                a0 = __builtin_amdgcn_mfma_f32_16x16x32_bf16(T[y + 2 * s], Bf[s][0], a0, 0, 0, 0);
                a1 = __builtin_amdgcn_mfma_f32_16x16x32_bf16(T[y + 2 * s], Bf[s][1], a1, 0, 0, 0);
            }
            pm0 = fmaxf(pm0, fmaxf(fmaxf(a0[0], a0[1]), fmaxf(a0[2], a0[3])));
            pm1 = fmaxf(pm1, fmaxf(fmaxf(a1[0], a1[1]), fmaxf(a1[2], a1[3])));
        }
        int px = xt * 4 + (l >> 4);
        if (px < 30) {
            int ob = ((b * 30 + py) * 30 + px) * 32 + m16;
            P1bf[ob]      = f2bf(pm0 + bias0);
            P1bf[ob + 16] = f2bf(pm1 + bias1);
        }
    }
}

// ---------------- kernel B (fallback): conv12m alone ----------------------
__global__ __launch_bounds__(256, 2) void k_conv12m(
    const float* __restrict__ x, const ushort_t* __restrict__ Wmf12,
    const float* __restrict__ B12, ushort_t* __restrict__ P1bf)
{
    __shared__ ushort_t sX[8 * 1880];
    conv12m_body(blockIdx.x, threadIdx.x, x, Wmf12, B12, P1bf, sX);
}

// ---------------- kernel B' (merged): conv12m || prep34s ------------------
__global__ __launch_bounds__(256, 2) void k_mid(
    const float* __restrict__ x, const ushort_t* __restrict__ Wmf12,
    const float* __restrict__ B12, ushort_t* __restrict__ P1bf,
    const float* __restrict__ Wpart, const float* __restrict__ Bpart,
    const float* __restrict__ b4,
    ushort_t* __restrict__ Wmf, float* __restrict__ B34)
{
    __shared__ ushort_t sX[8 * 1880];
    int t = threadIdx.x;
    if (blockIdx.x >= 1920) {
        int bid2 = blockIdx.x - 1920;
        int i = bid2 * 256 + t;
        if (i < 165888) {
            float s = 0.f;
            #pragma unroll
            for (int c = 0; c < 8; ++c) s += Wpart[c * 165888 + i];
            int oc = i & 63, r = i >> 6;
            int ic = r / 81, uv = r % 81;
            int idx = (uv * 16 + (oc >> 4) * 4 + (ic >> 3)) * 128
                    + (oc & 15) * 8 + (ic & 7);
            Wmf[idx] = f2bf(s);
        }
        if (bid2 == 648 && t < 64) {
            int oc = t;
            float s = b4[oc];
            #pragma unroll
            for (int c = 0; c < 8; ++c) s += Bpart[c * 64 + oc];
            B34[oc] = s;
        }
        return;
    }
    conv12m_body(blockIdx.x, t, x, Wmf12, B12, P1bf, sX);
}

// ---------------- kernel C: conv34 via MFMA + fused 4x4 pool -> emb -------
__global__ __launch_bounds__(320, 1) void k_conv34m(
    const ushort_t* __restrict__ P1bf, const ushort_t* __restrict__ Wmf,
    const float* __restrict__ B34, float* __restrict__ emb)
{
    __shared__ ushort_t sA[28 * 960];   // 53760 B

    int b  = blockIdx.x >> 2;
    int nt = blockIdx.x & 3;
    int t  = threadIdx.x;

    const uint4* gsrc = (const uint4*)(P1bf + b * 28800);
    for (int i = t; i < 3360; i += 320)
        ((uint4*)sA)[i] = gsrc[i];
    __syncthreads();

    int w  = t >> 6;          // wave = pool row py
    int l  = t & 63;
    int m16 = l & 15;
    int kc  = l >> 4;
    int iy = m16 >> 2, ix = m16 & 3;

    f32x4 acc0 = {0.f,0.f,0.f,0.f}, acc1 = acc0, acc2 = acc0,
          acc3 = acc0, acc4 = acc0;

    const ushort_t* wp = Wmf + (nt * 4 + kc) * 128 + m16 * 8;
    bf16x8 bcur = *(const bf16x8*)wp;
    int tap = 0;

    for (int ky = 0; ky < 9; ++ky) {
        const ushort_t* rp = sA + (w * 4 + iy + ky) * 960 + ix * 32 + kc * 8;
        bf16x8 T[25];
        #pragma unroll
        for (int cx = 0; cx < 25; ++cx)
            T[cx] = *(const bf16x8*)(rp + cx * 32);

        #pragma unroll
        for (int kx = 0; kx < 9; ++kx) {
            bf16x8 bnext = *(const bf16x8*)(wp + (tap + 1) * 2048);
            acc0 = __builtin_amdgcn_mfma_f32_16x16x32_bf16(T[kx],      bcur, acc0, 0, 0, 0);
            acc1 = __builtin_amdgcn_mfma_f32_16x16x32_bf16(T[kx + 4],  bcur, acc1, 0, 0, 0);
            acc2 = __builtin_amdgcn_mfma_f32_16x16x32_bf16(T[kx + 8],  bcur, acc2, 0, 0, 0);
            acc3 = __builtin_amdgcn_mfma_f32_16x16x32_bf16(T[kx + 12], bcur, acc3, 0, 0, 0);
            acc4 = __builtin_amdgcn_mfma_f32_16x16x32_bf16(T[kx + 16], bcur, acc4, 0, 0, 0);
            bcur = bnext;
            ++tap;
        }
    }

    float bias = B34[nt * 16 + m16];
    #pragma unroll
    for (int q = 0; q < 5; ++q) {
        f32x4 a = (q == 0) ? acc0 : (q == 1) ? acc1 : (q == 2) ? acc2
                : (q == 3) ? acc3 : acc4;
        float mv = fmaxf(fmaxf(a[0], a[1]), fmaxf(a[2], a[3]));
        mv = fmaxf(mv, __shfl_xor(mv, 16, 64));
        mv = fmaxf(mv, __shfl_xor(mv, 32, 64));
        if (l < 16) {
            int oc = nt * 16 + l;
            emb[b * 1600 + oc * 25 + w * 5 + q] = mv + bias;
        }
    }
}

// ---------------- kernel D: FC heads + cross-block final product ----------
// grid = 128 (head*64 + b); block = 512 = 2 K-halves x 256 j. (R19 proven)
// The SECOND block to finish batch b (tracked via cnt[b]) computes out[b].
__global__ __launch_bounds__(512) void k_fc(
    const float* __restrict__ emb,
    const float* __restrict__ w_ed1, const float* __restrict__ b_ed1,
    const float* __restrict__ w_ed2, const float* __restrict__ b_ed2,
    const float* __restrict__ w_ep1, const float* __restrict__ b_ep1,
    const float* __restrict__ w_ep2, const float* __restrict__ b_ep2,
    const int* __restrict__ esrc, const int* __restrict__ edst,
    float* __restrict__ logits, int* __restrict__ cnt,
    float* __restrict__ out)
{
    __shared__ float se[1600];
    __shared__ float sh[2][256];
    __shared__ float sred[2][4];

    int head = blockIdx.x >> 6;
    int b    = blockIdx.x & 63;
    int t    = threadIdx.x;
    int j    = t & 255;
    int kh   = t >> 8;                    // 0/1, wave-uniform

    {
        const float4* src = (const float4*)(emb + b * 1600);
        for (int i = t; i < 400; i += 512) ((float4*)se)[i] = src[i];
    }
    __syncthreads();

    const float* W1 = head ? w_ep1 : w_ed1;
    float a0 = 0.f, a1 = 0.f, a2 = 0.f, a3 = 0.f;
    int k0 = kh * 800;
    #pragma unroll 8
    for (int k = k0; k < k0 + 800; k += 4) {
        a0 = fmaf(se[k + 0], W1[(k + 0) * 256 + j], a0);
        a1 = fmaf(se[k + 1], W1[(k + 1) * 256 + j], a1);
        a2 = fmaf(se[k + 2], W1[(k + 2) * 256 + j], a2);
        a3 = fmaf(se[k + 3], W1[(k + 3) * 256 + j], a3);
    }
    sh[kh][j] = (a0 + a1) + (a2 + a3);
    __syncthreads();

    int c0 = esrc[0], c1 = edst[0];
    if (t < 256) {
        float bias1 = head ? b_ep1[j] : b_ed1[j];
        float h = fmaxf(bias1 + sh[0][j] + sh[1][j], 0.f);
        if (head == 0) {
            float p = h * w_ed2[j * 120];
            #pragma unroll
            for (int off = 32; off; off >>= 1) p += __shfl_down(p, off, 64);
            if ((t & 63) == 0) sred[0][t >> 6] = p;
        } else {
            float p0 = h * w_ep2[j * 36 + c0];
            float p1 = h * w_ep2[j * 36 + c1];
            #pragma unroll
            for (int off = 32; off; off >>= 1) {
                p0 += __shfl_down(p0, off, 64);
                p1 += __shfl_down(p1, off, 64);
            }
            if ((t & 63) == 0) {
                sred[0][t >> 6] = p0;
                sred[1][t >> 6] = p1;
            }
        }
    }
    __syncthreads();
    if (t == 0) {
        float s0 = (sred[0][0] + sred[0][1]) + (sred[0][2] + sred[0][3]);
        if (head == 0) {
            logits[b * 3 + 0] = s0 + b_ed2[0];
        } else {
            float s1 = (sred[1][0] + sred[1][1]) + (sred[1][2] + sred[1][3]);
            logits[b * 3 + 1] = s0 + b_ep2[c0];
            logits[b * 3 + 2] = s1 + b_ep2[c1];
        }
        __threadfence();                       // publish logits
        int old = atomicAdd(&cnt[b], 1);       // device-scope
        if (old == 1) {                        // second arriver finishes
            __threadfence();                   // acquire other block's logits
            float e  = logits[b * 3 + 0];
            float p0 = logits[b * 3 + 1];
            float p1 = logits[b * 3 + 2];
            out[b] = (1.f / (1.f + expf(-e))) *
                     (1.f / (1.f + expf(-p0))) *
                     (1.f / (1.f + expf(-p1)));
        }
    }
}

// ---------------- launch --------------------------------------------------
extern "C" void kernel_launch(void* const* d_in, const int* in_sizes, int n_in,
                              void* d_out, int out_size, void* d_ws, size_t ws_size,
                              hipStream_t stream)
{
    const float* x     = (const float*)d_in[0];
    const float* w1    = (const float*)d_in[1];
    const float* b1    = (const float*)d_in[2];
    const float* w2    = (const float*)d_in[3];
    const float* b2    = (const float*)d_in[4];
    const float* w3    = (const float*)d_in[5];
    const float* b3    = (const float*)d_in[6];
    const float* w4    = (const float*)d_in[7];
    const float* b4    = (const float*)d_in[8];
    const float* w_ed1 = (const float*)d_in[9];
    const float* b_ed1 = (const float*)d_in[10];
    const float* w_ed2 = (const float*)d_in[11];
    const float* b_ed2 = (const float*)d_in[12];
    const float* w_ep1 = (const float*)d_in[13];
    const float* b_ep1 = (const float*)d_in[14];
    const float* w_ep2 = (const float*)d_in[15];
    const float* b_ep2 = (const float*)d_in[16];
    const int*   esrc  = (const int*)d_in[17];
    const int*   edst  = (const int*)d_in[18];

    float* ws  = (float*)d_ws;
    float* out = (float*)d_out;

    ushort_t* Wmf12 = (ushort_t*)(ws + WS_WMF12);
    ushort_t* Wmf   = (ushort_t*)(ws + WS_WMF);

    if (ws_size >= (size_t)D_TOTAL * 4) {
        // ---- disjoint layout, merged middle kernel (4 launches) ----
        ushort_t* P1bf = (ushort_t*)(ws + D_P1);
        int* cnt = (int*)(ws + D_CNT);
        k_prepA<<<96, 256, 0, stream>>>(w1, b1, w2, b2, w3, b3, w4,
                                        ws + WS_B12, Wmf12,
                                        ws + D_WPART, ws + D_BPART, cnt);
        k_mid<<<1920 + 649, 256, 0, stream>>>(x, Wmf12, ws + WS_B12, P1bf,
                                              ws + D_WPART, ws + D_BPART, b4,
                                              Wmf, ws + WS_B34);
        k_conv34m<<<256, 320, 0, stream>>>(P1bf, Wmf, ws + WS_B34, ws + D_EMB);
        k_fc<<<128, 512, 0, stream>>>(ws + D_EMB, w_ed1, b_ed1, w_ed2, b_ed2,
                                      w_ep1, b_ep1, w_ep2, b_ep2, esrc, edst,
                                      ws + D_LOG, cnt, out);
    } else {
        // ---- overlay fallback: serial (5 launches) ----
        ushort_t* P1bf = (ushort_t*)(ws + O_P1);
        int* cnt = (int*)(ws + O_CNT);
        k_prepA<<<96, 256, 0, stream>>>(w1, b1, w2, b2, w3, b3, w4,
                                        ws + WS_B12, Wmf12,
                                        ws + O_WPART, ws + O_BPART, cnt);
        k_prep34s<<<649, 256, 0, stream>>>(ws + O_WPART, ws + O_BPART, b4,
                                           Wmf, ws + WS_B34);
        k_conv12m<<<64 * 30, 256, 0, stream>>>(x, Wmf12, ws + WS_B12, P1bf);
        k_conv34m<<<256, 320, 0, stream>>>(P1bf, Wmf, ws + WS_B34, ws + O_EMB);
        k_fc<<<128, 512, 0, stream>>>(ws + O_EMB, w_ed1, b_ed1, w_ed2, b_ed2,
                                      w_ep1, b_ep1, w_ep2, b_ep2, esrc, edst,
                                      ws + O_LOG, cnt, out);
    }
}

// Round 22
// 73.764 us; speedup vs baseline: 1.5032x; 1.0374x over previous
//
#include <hip/hip_runtime.h>
#include <math.h>

typedef __attribute__((ext_vector_type(8))) short bf16x8;
typedef __attribute__((ext_vector_type(4))) float f32x4;
typedef unsigned short ushort_t;

// ---------------- fixed workspace prefix (floats) ----------------
#define WS_B12   0                         // 32
#define WS_B34   32                        // 64
#define WS_WMF12 96                        // 2560 fl (5120 ushort)
#define WS_WMF   2656                      // 82944 fl (165888 ushort)
#define WS_FIX   85600                     // start of variable region

// Disjoint layout (needs ws_size >= 9.75 MB): NO overlays, safe for merged k_mid
#define D_WPART  WS_FIX                    // 1327104 fl
#define D_BPART  (WS_FIX + 1327104)        // 512
#define D_P1     (WS_FIX + 1327616)        // 921600 fl (bf16 x 1843200)
#define D_EMB    (D_P1 + 921600)           // 102400
#define D_LOG    (D_EMB + 102400)          // 192
#define D_TOTAL  (D_LOG + 192)             // 2437408 fl

// Overlay layout (fallback): Wpart overlays P1 region (serial ordering)
#define O_P1     WS_FIX                    // P1 bf16 in first 921600 fl
#define O_WPART  WS_FIX                    // [8][165888] (dead before conv12m)
#define O_BPART  (WS_FIX + 8*165888)
#define O_EMB    (WS_FIX + 1843200)
#define O_LOG    (O_EMB + 102400)

__device__ __forceinline__ unsigned short f2bf(float f) {
    unsigned u = __float_as_uint(f);
    u += 0x7FFF + ((u >> 16) & 1);         // RNE
    return (unsigned short)(u >> 16);
}

// ---------------- kernel A: prep12 (+Wmf12 pack)  ||  prep34 partials -----
__global__ __launch_bounds__(256) void k_prepA(
    const float* __restrict__ w1, const float* __restrict__ b1,
    const float* __restrict__ w2, const float* __restrict__ b2,
    const float* __restrict__ w3, const float* __restrict__ b3,
    const float* __restrict__ w4,
    float* __restrict__ B12, ushort_t* __restrict__ Wmf12,
    float* __restrict__ Wpart, float* __restrict__ Bpart)
{
    __shared__ float smem[13664];          // 54.7 KB
    int t = threadIdx.x;

    if (blockIdx.x < 32) {
        float* sW2  = smem;            // [mc*25+e]
        float* sW1  = smem + 800;
        float* sW12 = smem + 1600;     // [uv 81]
        int oc = blockIdx.x;
        for (int i = t; i < 800; i += 256) {
            sW2[i] = w2[oc * 800 + i];
            sW1[i] = w1[i];
        }
        __syncthreads();
        if (t < 81) {
            int u = t / 9, v = t % 9;
            float acc[4] = {0.f, 0.f, 0.f, 0.f};
            #pragma unroll
            for (int e = 0; e < 25; ++e) {
                int ey = e / 5, ex = e % 5;
                int du = u - ey, dv = v - ex;
                if ((unsigned)du <= 4u && (unsigned)dv <= 4u) {
                    int ep = du * 5 + dv;
                    for (int mc = 0; mc < 32; ++mc)
                        acc[e & 3] = fmaf(sW2[mc * 25 + e], sW1[mc * 25 + ep],
                                          acc[e & 3]);
                }
            }
            sW12[t] = (acc[0] + acc[1]) + (acc[2] + acc[3]);
        }
        if (t < 32) {
            float ws = 0.f;
            #pragma unroll
            for (int e = 0; e < 25; ++e) ws += sW2[t * 25 + e];
            float p = b1[t] * ws;
            #pragma unroll
            for (int off = 16; off; off >>= 1) p += __shfl_down(p, off, 64);
            if (t == 0) B12[oc] = p + b2[oc];
        }
        __syncthreads();
        if (t < 160) {                 // pack bf16 K-tap layout (pads = 0)
            int s  = t >> 5;
            int kc = (t >> 3) & 3;
            int e  = t & 7;
            int ky = 2 * s + (kc >> 1);
            int kx = 8 * (kc & 1) + e;
            float v = (ky <= 8 && kx <= 8) ? sW12[ky * 9 + kx] : 0.f;
            int so = s * 2 + (oc >> 4);
            int i2 = (so << 9) | (kc << 7) | ((oc & 15) << 3) | e;
            Wmf12[i2] = f2bf(v);
        }
    } else {
        float* sW4  = smem;            // [oc 64][201]
        float* sW3c = smem + 64 * 201; // [mcl 8][icl 4][e 25]
        int bid = blockIdx.x - 32;
        int icg = bid >> 3;
        int mcc = bid & 7;
        int oc  = t & 63;
        int icl = t >> 6;              // wave-uniform

        for (int i = t; i < 12800; i += 256) {
            int o = i / 200, r = i % 200;
            sW4[o * 201 + r] = w4[o * 1600 + mcc * 200 + r];
        }
        for (int i = t; i < 800; i += 256) {
            int mcl = i / 100, r = i % 100;
            sW3c[i] = w3[(mcc * 8 + mcl) * 800 + icg * 100 + r];
        }
        __syncthreads();

        float acc[81];
        #pragma unroll
        for (int u = 0; u < 81; ++u) acc[u] = 0.f;
        float bacc = 0.f;

        for (int mcl = 0; mcl < 8; ++mcl) {
            float w4r[25];
            #pragma unroll
            for (int e = 0; e < 25; ++e)
                w4r[e] = sW4[oc * 201 + mcl * 25 + e];
            const float* w3r = &sW3c[(mcl * 4 + icl) * 25];
            #pragma unroll
            for (int e2 = 0; e2 < 25; ++e2) {
                int ey = e2 / 5, ex = e2 % 5;
                #pragma unroll
                for (int e1 = 0; e1 < 25; ++e1) {
                    int u = (ey + e1 / 5) * 9 + (ex + e1 % 5); // compile-time
                    acc[u] = fmaf(w4r[e2], w3r[e1], acc[u]);
                }
            }
            if (icl == 0) {
                float ws = 0.f;
                #pragma unroll
                for (int e = 0; e < 25; ++e) ws += w4r[e];
                bacc = fmaf(b3[mcc * 8 + mcl], ws, bacc);
            }
        }

        int ic = icg * 4 + icl;
        for (int uv = 0; uv < 81; ++uv)
            Wpart[((mcc * 32 + ic) * 81 + uv) * 64 + oc] = acc[uv];
        if (icl == 0) Bpart[mcc * 64 + oc] = bacc;
    }
}

// ---------------- standalone prep34s (fallback path) ----------------------
__global__ __launch_bounds__(256) void k_prep34s(
    const float* __restrict__ Wpart, const float* __restrict__ Bpart,
    const float* __restrict__ b4,
    ushort_t* __restrict__ Wmf, float* __restrict__ B34)
{
    int i = blockIdx.x * 256 + threadIdx.x;
    if (i < 165888) {
        float s = 0.f;
        #pragma unroll
        for (int c = 0; c < 8; ++c) s += Wpart[c * 165888 + i];
        int oc = i & 63, r = i >> 6;
        int ic = r / 81, uv = r % 81;
        int idx = (uv * 16 + (oc >> 4) * 4 + (ic >> 3)) * 128
                + (oc & 15) * 8 + (ic & 7);
        Wmf[idx] = f2bf(s);
    }
    if (blockIdx.x == 648 && threadIdx.x < 64) {
        int oc = threadIdx.x;
        float s = b4[oc];
        #pragma unroll
        for (int c = 0; c < 8; ++c) s += Bpart[c * 64 + oc];
        B34[oc] = s;
    }
}

// ---------------- conv12m body (shared by k_conv12m and k_mid) ------------
__device__ __forceinline__ void conv12m_body(
    int bid, int t,
    const float* __restrict__ x, const ushort_t* __restrict__ Wmf12,
    const float* __restrict__ B12, ushort_t* __restrict__ P1bf,
    ushort_t* sX)
{
    int b  = bid / 30;
    int py = bid % 30;

    if (t < 221) {
        int rowL = t / 17, qg = t % 17;
        int absrow = 4 * py + rowL;
        if (absrow > 127) absrow = 127;
        const float* xr = x + (b * 128 + absrow) * 128;
        int c0 = qg * 8;
        float fs[16];
        #pragma unroll
        for (int q4 = 0; q4 < 4; ++q4) {
            int c = c0 + 4 * q4;
            float4 f;
            if (c <= 124) f = *(const float4*)(xr + c);
            else { f.x = 0.f; f.y = 0.f; f.z = 0.f; f.w = 0.f; }
            fs[4 * q4 + 0] = f.x; fs[4 * q4 + 1] = f.y;
            fs[4 * q4 + 2] = f.z; fs[4 * q4 + 3] = f.w;
        }
        unsigned d[8];
        #pragma unroll
        for (int j = 0; j < 8; ++j)
            d[j] = (unsigned)f2bf(fs[2 * j]) |
                   ((unsigned)f2bf(fs[2 * j + 1]) << 16);
        int eoff = rowL * 144 + c0;
        #pragma unroll
        for (int p = 0; p < 8; ++p) {
            uint4 wv;
            int k = p >> 1;
            if ((p & 1) == 0) {
                wv.x = d[k]; wv.y = d[k + 1]; wv.z = d[k + 2]; wv.w = d[k + 3];
            } else {
                wv.x = (d[k] >> 16)     | (d[k + 1] << 16);
                wv.y = (d[k + 1] >> 16) | (d[k + 2] << 16);
                wv.z = (d[k + 2] >> 16) | (d[k + 3] << 16);
                wv.w = (d[k + 3] >> 16) | (d[k + 4] << 16);
            }
            *(uint4*)(sX + p * 1880 + eoff) = wv;
        }
    }

    int l   = t & 63;
    int wv_ = t >> 6;
    int m16 = l & 15;
    int kc  = l >> 4;

    bf16x8 Bf[5][2];
    {
        const ushort_t* wb = Wmf12 + kc * 128 + m16 * 8;
        #pragma unroll
        for (int s = 0; s < 5; ++s)
            #pragma unroll
            for (int och = 0; och < 2; ++och)
                Bf[s][och] = *(const bf16x8*)(wb + (s * 2 + och) * 512);
    }
    float bias0 = B12[m16];
    float bias1 = B12[16 + m16];
    __syncthreads();

    int baseC = (m16 & 7) * 1880 + (kc >> 1) * 144
              + 8 * (m16 >> 3) + 8 * (kc & 1);

    #pragma unroll
    for (int xi = 0; xi < 2; ++xi) {
        int xt = wv_ * 2 + xi;
        const ushort_t* ap = sX + baseC + xt * 16;
        bf16x8 T[12];
        #pragma unroll
        for (int r = 0; r < 12; ++r)
            T[r] = *(const bf16x8*)(ap + r * 144);

        float pm0 = -INFINITY, pm1 = -INFINITY;
        #pragma unroll
        for (int y = 0; y < 4; ++y) {
            f32x4 a0 = {0.f, 0.f, 0.f, 0.f}, a1 = a0;
            #pragma unroll
            for (int s = 0; s < 5; ++s) {
                a0 = __builtin_amdgcn_mfma_f32_16x16x32_bf16(T[y + 2 * s], Bf[s][0], a0, 0, 0, 0);
                a1 = __builtin_amdgcn_mfma_f32_16x16x32_bf16(T[y + 2 * s], Bf[s][1], a1, 0, 0, 0);
            }
            pm0 = fmaxf(pm0, fmaxf(fmaxf(a0[0], a0[1]), fmaxf(a0[2], a0[3])));
            pm1 = fmaxf(pm1, fmaxf(fmaxf(a1[0], a1[1]), fmaxf(a1[2], a1[3])));
        }
        int px = xt * 4 + (l >> 4);
        if (px < 30) {
            int ob = ((b * 30 + py) * 30 + px) * 32 + m16;
            P1bf[ob]      = f2bf(pm0 + bias0);
            P1bf[ob + 16] = f2bf(pm1 + bias1);
        }
    }
}

// ---------------- kernel B (fallback): conv12m alone ----------------------
__global__ __launch_bounds__(256, 2) void k_conv12m(
    const float* __restrict__ x, const ushort_t* __restrict__ Wmf12,
    const float* __restrict__ B12, ushort_t* __restrict__ P1bf)
{
    __shared__ ushort_t sX[8 * 1880];
    conv12m_body(blockIdx.x, threadIdx.x, x, Wmf12, B12, P1bf, sX);
}

// ---------------- kernel B' (merged): conv12m || prep34s ------------------
// SAFE only with the disjoint layout (Wpart and P1bf non-overlapping).
__global__ __launch_bounds__(256, 2) void k_mid(
    const float* __restrict__ x, const ushort_t* __restrict__ Wmf12,
    const float* __restrict__ B12, ushort_t* __restrict__ P1bf,
    const float* __restrict__ Wpart, const float* __restrict__ Bpart,
    const float* __restrict__ b4,
    ushort_t* __restrict__ Wmf, float* __restrict__ B34)
{
    __shared__ ushort_t sX[8 * 1880];
    int t = threadIdx.x;
    if (blockIdx.x >= 1920) {
        int bid2 = blockIdx.x - 1920;
        int i = bid2 * 256 + t;
        if (i < 165888) {
            float s = 0.f;
            #pragma unroll
            for (int c = 0; c < 8; ++c) s += Wpart[c * 165888 + i];
            int oc = i & 63, r = i >> 6;
            int ic = r / 81, uv = r % 81;
            int idx = (uv * 16 + (oc >> 4) * 4 + (ic >> 3)) * 128
                    + (oc & 15) * 8 + (ic & 7);
            Wmf[idx] = f2bf(s);
        }
        if (bid2 == 648 && t < 64) {
            int oc = t;
            float s = b4[oc];
            #pragma unroll
            for (int c = 0; c < 8; ++c) s += Bpart[c * 64 + oc];
            B34[oc] = s;
        }
        return;
    }
    conv12m_body(blockIdx.x, t, x, Wmf12, B12, P1bf, sX);
}

// ---------------- kernel C: conv34 via MFMA + fused 4x4 pool -> emb -------
__global__ __launch_bounds__(320, 1) void k_conv34m(
    const ushort_t* __restrict__ P1bf, const ushort_t* __restrict__ Wmf,
    const float* __restrict__ B34, float* __restrict__ emb)
{
    __shared__ ushort_t sA[28 * 960];   // 53760 B

    int b  = blockIdx.x >> 2;
    int nt = blockIdx.x & 3;
    int t  = threadIdx.x;

    const uint4* gsrc = (const uint4*)(P1bf + b * 28800);
    for (int i = t; i < 3360; i += 320)
        ((uint4*)sA)[i] = gsrc[i];
    __syncthreads();

    int w  = t >> 6;          // wave = pool row py
    int l  = t & 63;
    int m16 = l & 15;
    int kc  = l >> 4;
    int iy = m16 >> 2, ix = m16 & 3;

    f32x4 acc0 = {0.f,0.f,0.f,0.f}, acc1 = acc0, acc2 = acc0,
          acc3 = acc0, acc4 = acc0;

    const ushort_t* wp = Wmf + (nt * 4 + kc) * 128 + m16 * 8;
    bf16x8 bcur = *(const bf16x8*)wp;
    int tap = 0;

    for (int ky = 0; ky < 9; ++ky) {
        const ushort_t* rp = sA + (w * 4 + iy + ky) * 960 + ix * 32 + kc * 8;
        bf16x8 T[25];
        #pragma unroll
        for (int cx = 0; cx < 25; ++cx)
            T[cx] = *(const bf16x8*)(rp + cx * 32);

        #pragma unroll
        for (int kx = 0; kx < 9; ++kx) {
            bf16x8 bnext = *(const bf16x8*)(wp + (tap + 1) * 2048);
            acc0 = __builtin_amdgcn_mfma_f32_16x16x32_bf16(T[kx],      bcur, acc0, 0, 0, 0);
            acc1 = __builtin_amdgcn_mfma_f32_16x16x32_bf16(T[kx + 4],  bcur, acc1, 0, 0, 0);
            acc2 = __builtin_amdgcn_mfma_f32_16x16x32_bf16(T[kx + 8],  bcur, acc2, 0, 0, 0);
            acc3 = __builtin_amdgcn_mfma_f32_16x16x32_bf16(T[kx + 12], bcur, acc3, 0, 0, 0);
            acc4 = __builtin_amdgcn_mfma_f32_16x16x32_bf16(T[kx + 16], bcur, acc4, 0, 0, 0);
            bcur = bnext;
            ++tap;
        }
    }

    float bias = B34[nt * 16 + m16];
    #pragma unroll
    for (int q = 0; q < 5; ++q) {
        f32x4 a = (q == 0) ? acc0 : (q == 1) ? acc1 : (q == 2) ? acc2
                : (q == 3) ? acc3 : acc4;
        float mv = fmaxf(fmaxf(a[0], a[1]), fmaxf(a[2], a[3]));
        mv = fmaxf(mv, __shfl_xor(mv, 16, 64));
        mv = fmaxf(mv, __shfl_xor(mv, 32, 64));
        if (l < 16) {
            int oc = nt * 16 + l;
            emb[b * 1600 + oc * 25 + w * 5 + q] = mv + bias;
        }
    }
}

// ---------------- kernel D: FC heads fused (fc1 + needed fc2 cols) --------
// grid = 128 (head*64 + b); block = 512 = 2 K-halves x 256 j. (R12/R14 proven)
__global__ __launch_bounds__(512) void k_fc(
    const float* __restrict__ emb,
    const float* __restrict__ w_ed1, const float* __restrict__ b_ed1,
    const float* __restrict__ w_ed2, const float* __restrict__ b_ed2,
    const float* __restrict__ w_ep1, const float* __restrict__ b_ep1,
    const float* __restrict__ w_ep2, const float* __restrict__ b_ep2,
    const int* __restrict__ esrc, const int* __restrict__ edst,
    float* __restrict__ logits)
{
    __shared__ float se[1600];
    __shared__ float sh[2][256];
    __shared__ float sred[2][4];

    int head = blockIdx.x >> 6;
    int b    = blockIdx.x & 63;
    int t    = threadIdx.x;
    int j    = t & 255;
    int kh   = t >> 8;                    // 0/1, wave-uniform

    {
        const float4* src = (const float4*)(emb + b * 1600);
        for (int i = t; i < 400; i += 512) ((float4*)se)[i] = src[i];
    }
    __syncthreads();

    const float* W1 = head ? w_ep1 : w_ed1;
    float a0 = 0.f, a1 = 0.f, a2 = 0.f, a3 = 0.f;
    int k0 = kh * 800;
    #pragma unroll 8
    for (int k = k0; k < k0 + 800; k += 4) {
        a0 = fmaf(se[k + 0], W1[(k + 0) * 256 + j], a0);
        a1 = fmaf(se[k + 1], W1[(k + 1) * 256 + j], a1);
        a2 = fmaf(se[k + 2], W1[(k + 2) * 256 + j], a2);
        a3 = fmaf(se[k + 3], W1[(k + 3) * 256 + j], a3);
    }
    sh[kh][j] = (a0 + a1) + (a2 + a3);
    __syncthreads();

    int c0 = esrc[0], c1 = edst[0];
    if (t < 256) {
        float bias1 = head ? b_ep1[j] : b_ed1[j];
        float h = fmaxf(bias1 + sh[0][j] + sh[1][j], 0.f);
        if (head == 0) {
            float p = h * w_ed2[j * 120];
            #pragma unroll
            for (int off = 32; off; off >>= 1) p += __shfl_down(p, off, 64);
            if ((t & 63) == 0) sred[0][t >> 6] = p;
        } else {
            float p0 = h * w_ep2[j * 36 + c0];
            float p1 = h * w_ep2[j * 36 + c1];
            #pragma unroll
            for (int off = 32; off; off >>= 1) {
                p0 += __shfl_down(p0, off, 64);
                p1 += __shfl_down(p1, off, 64);
            }
            if ((t & 63) == 0) {
                sred[0][t >> 6] = p0;
                sred[1][t >> 6] = p1;
            }
        }
    }
    __syncthreads();
    if (t == 0) {
        float s0 = (sred[0][0] + sred[0][1]) + (sred[0][2] + sred[0][3]);
        if (head == 0) {
            logits[b * 3 + 0] = s0 + b_ed2[0];
        } else {
            float s1 = (sred[1][0] + sred[1][1]) + (sred[1][2] + sred[1][3]);
            logits[b * 3 + 1] = s0 + b_ep2[c0];
            logits[b * 3 + 2] = s1 + b_ep2[c1];
        }
    }
}

// ---------------- kernel E: sigmoid products -> out ----------------------
__global__ __launch_bounds__(64) void k_final(
    const float* __restrict__ logits, float* __restrict__ out)
{
    int b = threadIdx.x;
    if (b < 64) {
        float e  = logits[b * 3 + 0];
        float p0 = logits[b * 3 + 1];
        float p1 = logits[b * 3 + 2];
        out[b] = (1.f / (1.f + expf(-e))) *
                 (1.f / (1.f + expf(-p0))) *
                 (1.f / (1.f + expf(-p1)));
    }
}

// ---------------- launch --------------------------------------------------
extern "C" void kernel_launch(void* const* d_in, const int* in_sizes, int n_in,
                              void* d_out, int out_size, void* d_ws, size_t ws_size,
                              hipStream_t stream)
{
    const float* x     = (const float*)d_in[0];
    const float* w1    = (const float*)d_in[1];
    const float* b1    = (const float*)d_in[2];
    const float* w2    = (const float*)d_in[3];
    const float* b2    = (const float*)d_in[4];
    const float* w3    = (const float*)d_in[5];
    const float* b3    = (const float*)d_in[6];
    const float* w4    = (const float*)d_in[7];
    const float* b4    = (const float*)d_in[8];
    const float* w_ed1 = (const float*)d_in[9];
    const float* b_ed1 = (const float*)d_in[10];
    const float* w_ed2 = (const float*)d_in[11];
    const float* b_ed2 = (const float*)d_in[12];
    const float* w_ep1 = (const float*)d_in[13];
    const float* b_ep1 = (const float*)d_in[14];
    const float* w_ep2 = (const float*)d_in[15];
    const float* b_ep2 = (const float*)d_in[16];
    const int*   esrc  = (const int*)d_in[17];
    const int*   edst  = (const int*)d_in[18];

    float* ws  = (float*)d_ws;
    float* out = (float*)d_out;

    ushort_t* Wmf12 = (ushort_t*)(ws + WS_WMF12);
    ushort_t* Wmf   = (ushort_t*)(ws + WS_WMF);

    if (ws_size >= (size_t)D_TOTAL * 4) {
        // ---- disjoint layout, merged middle kernel (5 launches) ----
        ushort_t* P1bf = (ushort_t*)(ws + D_P1);
        k_prepA<<<96, 256, 0, stream>>>(w1, b1, w2, b2, w3, b3, w4,
                                        ws + WS_B12, Wmf12,
                                        ws + D_WPART, ws + D_BPART);
        k_mid<<<1920 + 649, 256, 0, stream>>>(x, Wmf12, ws + WS_B12, P1bf,
                                              ws + D_WPART, ws + D_BPART, b4,
                                              Wmf, ws + WS_B34);
        k_conv34m<<<256, 320, 0, stream>>>(P1bf, Wmf, ws + WS_B34, ws + D_EMB);
        k_fc<<<128, 512, 0, stream>>>(ws + D_EMB, w_ed1, b_ed1, w_ed2, b_ed2,
                                      w_ep1, b_ep1, w_ep2, b_ep2, esrc, edst,
                                      ws + D_LOG);
        k_final<<<1, 64, 0, stream>>>(ws + D_LOG, out);
    } else {
        // ---- R17 fallback: overlay layout, serial (6 launches) ----
        ushort_t* P1bf = (ushort_t*)(ws + O_P1);
        k_prepA<<<96, 256, 0, stream>>>(w1, b1, w2, b2, w3, b3, w4,
                                        ws + WS_B12, Wmf12,
                                        ws + O_WPART, ws + O_BPART);
        k_prep34s<<<649, 256, 0, stream>>>(ws + O_WPART, ws + O_BPART, b4,
                                           Wmf, ws + WS_B34);
        k_conv12m<<<64 * 30, 256, 0, stream>>>(x, Wmf12, ws + WS_B12, P1bf);
        k_conv34m<<<256, 320, 0, stream>>>(P1bf, Wmf, ws + WS_B34, ws + O_EMB);
        k_fc<<<128, 512, 0, stream>>>(ws + O_EMB, w_ed1, b_ed1, w_ed2, b_ed2,
                                      w_ep1, b_ep1, w_ep2, b_ep2, esrc, edst,
                                      ws + O_LOG);
        k_final<<<1, 64, 0, stream>>>(ws + O_LOG, out);
    }
}